// Round 9
// baseline (26818.408 us; speedup 1.0000x reference)
//
#include <hip/hip_runtime.h>

#define NB 64    // batch
#define NT 512   // timesteps
#define NI 256   // input dim
#define NH 1024  // hidden dim
#define NO 256   // output dim
#define NWG 64   // workgroups in cooperative kernel
#define NTHR 1024
#define NU 16    // hidden units per WG (NWG*NU == NH)
#define NR 64    // gate rows per WG = 4*NU
#define NGRP 8   // barrier tree: groups
#define GSZ 8    // barrier tree: WGs per group

typedef __attribute__((ext_vector_type(8))) __bf16 bf16x8;
typedef __attribute__((ext_vector_type(8))) unsigned short u16x8;
typedef __attribute__((ext_vector_type(16))) float f32x16;

union FragQ { unsigned long long q[2]; bf16x8 v; };

static __device__ __forceinline__ unsigned short f2bf(float f) {
  unsigned int u = __float_as_uint(f);
  unsigned int r = (u + 0x7fffu + ((u >> 16) & 1u)) >> 16;  // RNE
  return (unsigned short)r;
}

static __device__ __forceinline__ f32x16 zero16() {
  f32x16 z;
#pragma unroll
  for (int i = 0; i < 16; ++i) z[i] = 0.f;
  return z;
}

// Barrier counters in d_out: root at word 0, group g at word (g+1)*32
// (one 128B line each). Per-WG-gathered W_ih bf16 at byte 4096 of d_out.
// Both regions are rewritten by xpose each call, consumed by lstm, then
// overwritten by outproj's y at the end.

// ---------------------------------------------------------------- prep
// x [B][T][I] fp32 -> xbf [T][B][I] bf16.
// Wih [4H][I] fp32 -> wihbf [NWG][NR][NI] bf16, PRE-GATHERED per WG:
//   row r of WG w  =  Wih[(r>>4)*NH + w*NU + (r&15)]   (gate g=r>>4, unit r&15)
// Also zeroes the 9 barrier counters.
__global__ void __launch_bounds__(256) xpose_kernel(const float* __restrict__ x,
                                                    const float* __restrict__ Wih,
                                                    unsigned short* __restrict__ xbf,
                                                    unsigned short* __restrict__ wihbf,
                                                    unsigned int* __restrict__ bar) {
  if (blockIdx.x == 0 && threadIdx.x < 1 + NGRP)
    __hip_atomic_store(bar + threadIdx.x * 32, 0u, __ATOMIC_RELAXED, __HIP_MEMORY_SCOPE_AGENT);
  int idx = blockIdx.x * 256 + threadIdx.x;
  const int total = NB * NT * NI / 8;
  for (int e = idx; e < total; e += gridDim.x * 256) {
    int i8 = (e & 31) * 8;      // I/8 = 32 groups per row
    int tb = e >> 5;            // t*NB + b
    int b = tb & (NB - 1);
    int t = tb >> 6;
    const float* src = x + ((b * NT + t) << 8) + i8;
    u16x8 v;
#pragma unroll
    for (int j = 0; j < 8; ++j) v[j] = f2bf(src[j]);
    *(u16x8*)(xbf + e * 8) = v;
  }
  // W_ih gather: e indexes (w, r, k8): w = e>>11, r = (e>>5)&63, k8 = e&31
  const int wtotal = NWG * NR * NI / 8;  // 131072
  for (int e = idx; e < wtotal; e += gridDim.x * 256) {
    int k8 = (e & 31) * 8;
    int r = (e >> 5) & (NR - 1);
    int w = e >> 11;
    const float* src = Wih + ((size_t)((r >> 4) * NH + w * NU + (r & 15))) * NI + k8;
    u16x8 v;
#pragma unroll
    for (int j = 0; j < 8; ++j) v[j] = f2bf(src[j]);
    *(u16x8*)(wihbf + (size_t)e * 8) = v;
  }
}

// ---------------------------------------------------------------- LSTM (coop)
// 64 WGs x 1024 thr; each WG owns NU=16 hidden units (NR=64 gate rows).
// W_hh slice bf16 in LDS (128 KB, XOR-swizzled); c-state in registers.
// MFMA 32x32x16. Waves: wid = (m in 2) | (qq in 8)<<1: output batch-half m,
// K-eighth qq, both 32-row N-tiles; partials merged by ds_add_f32 into a
// swizzled zbuf. h exchanged via agent-scope (sc1, LLC) loads/stores; sync
// via 2-level relaxed-atomic tree (8x8) with explicit vmcnt(0) drain.
__global__ void __launch_bounds__(1024) lstm_kernel(
    const unsigned short* __restrict__ xbf,    // [T][B][I] bf16
    const unsigned short* __restrict__ wihbf,  // [NWG][NR][NI] bf16 (gathered)
    const float* __restrict__ Whh,             // [4H][H]
    const float* __restrict__ bih,
    const float* __restrict__ bhh,
    unsigned short* __restrict__ hall,         // [T][B][H] bf16
    unsigned int* __restrict__ bar) {
  __shared__ __align__(16) unsigned short Wh_l[NR * NH];    // 128 KB
  __shared__ float zbuf[NB][NB];                            // 16 KB
  __shared__ float bias_l[NR];
  __shared__ __align__(16) unsigned short hstage[NB * NU];  // 2 KB

  const int tid = threadIdx.x;
  const int u0 = blockIdx.x * NU;
  const int grp = blockIdx.x >> 3;  // 8 WGs per barrier group

  // Stage W_hh slice fp32->bf16, swizzled: k ^= (row&15)<<3 (2-way banks max)
  for (int idx = tid; idx < NR * NH; idx += NTHR) {
    int r = idx >> 10, k = idx & (NH - 1);
    int g = r >> 4, uu = r & 15;
    Wh_l[(r << 10) | (k ^ ((r & 15) << 3))] = f2bf(Whh[(g * NH + u0 + uu) * NH + k]);
  }
  if (tid < NR) {
    int g = tid >> 4, uu = tid & 15;
    bias_l[tid] = bih[g * NH + u0 + uu] + bhh[g * NH + u0 + uu];
  }
  for (int idx = tid; idx < NB * NB; idx += NTHR) ((float*)zbuf)[idx] = 0.f;
  __syncthreads();

  const int wid = tid >> 6, lane = tid & 63;
  const int m = wid & 1;    // batch half (32 rows)
  const int qq = wid >> 1;  // K-eighth (128 of 1024 h / 32 of 256 x)
  const int lo = lane & 31, hi = lane >> 5;
  const int eb = tid >> 4, eu = tid & 15;  // elementwise (batch, unit)
  float c_state = 0.f;
  const int swz = (lo & 15) << 3;  // same for rows lo and 32+lo

  const unsigned short* whr0 = Wh_l + lo * NH;
  const unsigned short* whr1 = Wh_l + (32 + lo) * NH;
  // This WG's gathered W_ih rows: wih_wg + row*NI + k
  const unsigned short* wih_wg = wihbf + (size_t)blockIdx.x * NR * NI;

  f32x16 axA, axB;
#define COMPUTE_AX(T_)                                                          \
  do {                                                                          \
    axA = zero16(); axB = zero16();                                             \
    const unsigned short* xrow = xbf + ((T_) * NB + m * 32 + lo) * NI + qq * 32 + hi * 8; \
    const unsigned short* w0r = wih_wg + lo * NI + qq * 32 + hi * 8;            \
    const unsigned short* w1r = wih_wg + (32 + lo) * NI + qq * 32 + hi * 8;     \
    _Pragma("unroll")                                                           \
    for (int ks = 0; ks < 2; ++ks) {                                            \
      bf16x8 a = *(const bf16x8*)(xrow + ks * 16);                              \
      bf16x8 w0 = *(const bf16x8*)(w0r + ks * 16);                              \
      bf16x8 w1 = *(const bf16x8*)(w1r + ks * 16);                              \
      axA = __builtin_amdgcn_mfma_f32_32x32x16_bf16(a, w0, axA, 0, 0, 0);       \
      axB = __builtin_amdgcn_mfma_f32_32x32x16_bf16(a, w1, axB, 0, 0, 0);       \
    }                                                                           \
  } while (0)

  COMPUTE_AX(0);

  for (int t = 0; t < NT; ++t) {
    f32x16 accA = axA, accB = axB;
    // h contribution: A row = m*32+lo (batch), k = qq*128 + ks*16 + hi*8.
    // sc1 loads: bypass stale-capable L2, read LLC.
    if (t > 0) {
      const unsigned long long* hrow =
          (const unsigned long long*)(hall + ((size_t)(t - 1) * NB + m * 32 + lo) * NH) +
          qq * 32 + hi * 2;
#pragma unroll
      for (int ks = 0; ks < 8; ++ks) {
        FragQ a;
        a.q[0] = __hip_atomic_load(hrow + ks * 4, __ATOMIC_RELAXED, __HIP_MEMORY_SCOPE_AGENT);
        a.q[1] = __hip_atomic_load(hrow + ks * 4 + 1, __ATOMIC_RELAXED, __HIP_MEMORY_SCOPE_AGENT);
        int koff = qq * 128 + ks * 16 + hi * 8;
        bf16x8 b0 = *(const bf16x8*)(whr0 + (koff ^ swz));
        bf16x8 b1 = *(const bf16x8*)(whr1 + (koff ^ swz));
        accA = __builtin_amdgcn_mfma_f32_32x32x16_bf16(a.v, b0, accA, 0, 0, 0);
        accB = __builtin_amdgcn_mfma_f32_32x32x16_bf16(a.v, b1, accB, 0, 0, 0);
      }
    }
    // Merge K-eighth partials: D col=lo (gate row), row=(r&3)+8*(r>>2)+4*hi.
    // zbuf col swizzle ((brow&3)<<4) keeps both ds_add and readback ~2-way.
#pragma unroll
    for (int r = 0; r < 16; ++r) {
      int brow = m * 32 + (r & 3) + ((r >> 2) << 3) + (hi << 2);
      int sw = (brow & 3) << 4;
      atomicAdd(&zbuf[brow][lo ^ sw], accA[r]);
      atomicAdd(&zbuf[brow][(32 + lo) ^ sw], accB[r]);
    }
    __syncthreads();

    // Elementwise: one (batch,unit) per thread; read 4 gates, zero in place.
    {
      int sw = (eb & 3) << 4;
      float zi = zbuf[eb][(0 * 16 + eu) ^ sw] + bias_l[0 * 16 + eu];
      float zf = zbuf[eb][(1 * 16 + eu) ^ sw] + bias_l[1 * 16 + eu];
      float zg = zbuf[eb][(2 * 16 + eu) ^ sw] + bias_l[2 * 16 + eu];
      float zo = zbuf[eb][(3 * 16 + eu) ^ sw] + bias_l[3 * 16 + eu];
      zbuf[eb][(0 * 16 + eu) ^ sw] = 0.f;
      zbuf[eb][(1 * 16 + eu) ^ sw] = 0.f;
      zbuf[eb][(2 * 16 + eu) ^ sw] = 0.f;
      zbuf[eb][(3 * 16 + eu) ^ sw] = 0.f;
      float ig = 1.f / (1.f + __expf(-zi));
      float fg = 1.f / (1.f + __expf(-zf));
      float gg = tanhf(zg);
      float og = 1.f / (1.f + __expf(-zo));
      c_state = fg * c_state + ig * gg;
      hstage[eb * NU + eu] = f2bf(og * tanhf(c_state));
    }
    __syncthreads();

    // Wave 0 publishes this WG's h-slice: 64 lanes x 32 B, sc1 -> LLC.
    if (wid == 0) {
      const unsigned long long* s = (const unsigned long long*)(hstage + lane * NU);
      unsigned long long* dst = (unsigned long long*)(hall + ((size_t)t * NB + lane) * NH + u0);
#pragma unroll
      for (int i = 0; i < 4; ++i)
        __hip_atomic_store(dst + i, s[i], __ATOMIC_RELAXED, __HIP_MEMORY_SCOPE_AGENT);
    }
    // Tree arrival: drain wave-0 h-stores via vmcnt, relaxed group add,
    // last-of-8 bumps root. No cache-maintenance ops.
    if (tid == 0) {
      asm volatile("s_waitcnt vmcnt(0)" ::: "memory");
      unsigned int old = __hip_atomic_fetch_add(bar + (grp + 1) * 32, 1u,
                                                __ATOMIC_RELAXED, __HIP_MEMORY_SCOPE_AGENT);
      if (old == (unsigned int)(t * GSZ + (GSZ - 1)))
        __hip_atomic_fetch_add(bar, 1u, __ATOMIC_RELAXED, __HIP_MEMORY_SCOPE_AGENT);
    }
    // Next step's x-MFMAs in the barrier shadow (h-independent).
    if (t + 1 < NT) COMPUTE_AX(t + 1);
    if (tid == 0) {
      const unsigned int target = (unsigned int)(t + 1) * NGRP;
      while (__hip_atomic_load(bar, __ATOMIC_RELAXED, __HIP_MEMORY_SCOPE_AGENT) < target)
        __builtin_amdgcn_s_sleep(1);
    }
    __syncthreads();
  }
#undef COMPUTE_AX
}

// ---------------------------------------------------------------- y = h @ Wout^T + b
typedef __attribute__((ext_vector_type(4))) float f32x4;
__global__ void __launch_bounds__(256) outproj_kernel(
    const unsigned short* __restrict__ hall,  // [T*B][H] bf16
    const float* __restrict__ Wout,           // [O][H]
    const float* __restrict__ bout,           // [O]
    float* __restrict__ y) {                  // [B][T][O] fp32
  __shared__ __align__(16) unsigned short At[64 * 64];
  __shared__ __align__(16) unsigned short Bt[64 * 64];
  const int tid = threadIdx.x;
  const int row0 = blockIdx.x * 64;
  const int col0 = blockIdx.y * 64;
  const int wave = tid >> 6, lane = tid & 63, lr = lane & 15, lq = lane >> 4;
  f32x4 acc[4];
#pragma unroll
  for (int n = 0; n < 4; ++n) acc[n] = (f32x4){0.f, 0.f, 0.f, 0.f};
  const int rr = tid >> 4;
  const int kk4 = (tid & 15) * 4;

  for (int kc = 0; kc < NH / 64; ++kc) {
#pragma unroll
    for (int p = 0; p < 4; ++p) {
      int r = rr + p * 16;
      ushort4 va = *(const ushort4*)(hall + (size_t)(row0 + r) * NH + kc * 64 + kk4);
      *(ushort4*)(At + r * 64 + (kk4 ^ ((r & 7) << 3))) = va;
      float4 vb = *(const float4*)(Wout + (size_t)(col0 + r) * NH + kc * 64 + kk4);
      ushort4 wb;
      wb.x = f2bf(vb.x); wb.y = f2bf(vb.y); wb.z = f2bf(vb.z); wb.w = f2bf(vb.w);
      *(ushort4*)(Bt + r * 64 + (kk4 ^ ((r & 7) << 3))) = wb;
    }
    __syncthreads();
#pragma unroll
    for (int kk = 0; kk < 2; ++kk) {
      int kb = kk * 32 + lq * 8;
      typedef __attribute__((ext_vector_type(8))) __bf16 bf8;
      bf8 af = *(const bf8*)(At + (wave * 16 + lr) * 64 + (kb ^ ((lr & 7) << 3)));
#pragma unroll
      for (int n = 0; n < 4; ++n) {
        bf8 bf = *(const bf8*)(Bt + (n * 16 + lr) * 64 + (kb ^ ((lr & 7) << 3)));
        acc[n] = __builtin_amdgcn_mfma_f32_16x16x32_bf16(af, bf, acc[n], 0, 0, 0);
      }
    }
    __syncthreads();
  }
#pragma unroll
  for (int n = 0; n < 4; ++n) {
    int o = col0 + n * 16 + lr;
    float bo = bout[o];
#pragma unroll
    for (int j = 0; j < 4; ++j) {
      int r = row0 + wave * 16 + lq * 4 + j;  // r = t*NB + b
      int b = r & (NB - 1);
      int t = r >> 6;
      y[(size_t)((b << 9) | t) * NO + o] = acc[n][j] + bo;
    }
  }
}

// ---------------------------------------------------------------- launch
extern "C" void kernel_launch(void* const* d_in, const int* in_sizes, int n_in,
                              void* d_out, int out_size, void* d_ws, size_t ws_size,
                              hipStream_t stream) {
  const float* x    = (const float*)d_in[0];
  const float* Wih  = (const float*)d_in[1];
  const float* Whh  = (const float*)d_in[2];
  const float* bih  = (const float*)d_in[3];
  const float* bhh  = (const float*)d_in[4];
  const float* Wout = (const float*)d_in[5];
  const float* bout = (const float*)d_in[6];
  float* y = (float*)d_out;

  // ws layout: xbf (16 MB) | hall (64 MB)  => 80 MB (known-good footprint)
  unsigned short* xbf  = (unsigned short*)d_ws;
  unsigned short* hall = xbf + (size_t)NT * NB * NI;
  // d_out scratch (rewritten each call, overwritten by y at the end):
  // barrier counters at byte 0, gathered bf16 W_ih at byte 4096 (2 MB).
  unsigned int* bar = (unsigned int*)d_out;
  unsigned short* wihbf = (unsigned short*)((char*)d_out + 4096);

  hipLaunchKernelGGL(xpose_kernel, dim3(1024), dim3(256), 0, stream,
                     x, Wih, xbf, wihbf, bar);

  void* args[7];
  args[0] = (void*)&xbf;
  args[1] = (void*)&wihbf;
  args[2] = (void*)&Whh;
  args[3] = (void*)&bih;
  args[4] = (void*)&bhh;
  args[5] = (void*)&hall;
  args[6] = (void*)&bar;
  hipLaunchCooperativeKernel(lstm_kernel, dim3(NWG), dim3(NTHR), args, 0u, stream);

  hipLaunchKernelGGL(outproj_kernel, dim3(512, 4), dim3(256), 0, stream,
                     hall, Wout, bout, y);
}

// Round 10
// 3612.429 us; speedup vs baseline: 7.4239x; 7.4239x over previous
//
#include <hip/hip_runtime.h>

#define NB 64    // batch
#define NT 512   // timesteps
#define NI 256   // input dim
#define NH 1024  // hidden dim
#define NO 256   // output dim
#define NWG 256  // workgroups in cooperative kernel
#define NU 4     // hidden units per WG (NWG*NU == NH)
#define NR 16    // gate rows per WG = 4*NU
#define NGRP 16  // barrier tree: groups
#define GSZ 16   // barrier tree: WGs per group

typedef __attribute__((ext_vector_type(8))) __bf16 bf16x8;
typedef __attribute__((ext_vector_type(8))) unsigned short u16x8;
typedef __attribute__((ext_vector_type(4))) float f32x4;

union FragQ { unsigned long long q[2]; bf16x8 v; };

static __device__ __forceinline__ unsigned short f2bf(float f) {
  unsigned int u = __float_as_uint(f);
  unsigned int r = (u + 0x7fffu + ((u >> 16) & 1u)) >> 16;  // RNE
  return (unsigned short)r;
}

// Barrier counter layout inside bar[] (uint32): root at [0], group g at
// [(g+1)*32] -- one 128B cacheline per counter, no false sharing.

// ---------------------------------------------------------------- x transpose
// x [B][T][I] fp32 -> xbf [T][B][I] bf16; zeroes the 17 barrier counters.
__global__ void __launch_bounds__(256) xpose_kernel(const float* __restrict__ x,
                                                    unsigned short* __restrict__ xbf,
                                                    unsigned int* __restrict__ bar) {
  if (blockIdx.x == 0 && threadIdx.x < 1 + NGRP)
    __hip_atomic_store(bar + threadIdx.x * 32, 0u, __ATOMIC_RELAXED, __HIP_MEMORY_SCOPE_AGENT);
  int idx = blockIdx.x * 256 + threadIdx.x;
  const int total = NB * NT * NI / 8;
  for (int e = idx; e < total; e += gridDim.x * 256) {
    int i8 = (e & 31) * 8;      // I/8 = 32 groups per row
    int tb = e >> 5;            // t*NB + b
    int b = tb & (NB - 1);
    int t = tb >> 6;
    const float* src = x + ((b * NT + t) << 8) + i8;
    u16x8 v;
#pragma unroll
    for (int j = 0; j < 8; ++j) v[j] = f2bf(src[j]);
    *(u16x8*)(xbf + e * 8) = v;
  }
}

// ---------------------------------------------------------------- LSTM (coop)
// R6-proven structure. ONE change vs R6: h-loads are PLAIN cached loads
// (L2 per XCD amortizes the broadcast 32x) instead of sc1 LLC-direct.
// Safe because hall is append-only: each step's 128KB region is written
// exactly once (sc1 write-through) and only read after the barrier; no L2
// line can be stale (kernel-dispatch acquire invalidated pre-kernel state).
// Producer side unchanged: sc1 publish + vmcnt(0) drain + relaxed tree
// barrier (16 groups x 16) -- zero cache-maintenance ops per step.
__global__ void __launch_bounds__(512) lstm_kernel(
    const unsigned short* __restrict__ xbf,   // [T][B][I] bf16
    const float* __restrict__ Wih,            // [4H][I]
    const float* __restrict__ Whh,            // [4H][H]
    const float* __restrict__ bih,
    const float* __restrict__ bhh,
    unsigned short* __restrict__ hall,        // [T][B][H] bf16
    unsigned int* __restrict__ bar) {
  __shared__ __align__(16) unsigned short Wh_l[NR * NH];   // 32 KB
  __shared__ __align__(16) unsigned short Wi_l[NR * NI];   // 8 KB
  __shared__ float bias_l[NR];
  __shared__ float zbuf[2][NB][17];                        // pad 17: kill bank conflicts
  __shared__ __align__(16) unsigned short hstage[NB * NU]; // 512 B

  const int tid = threadIdx.x;
  const int u0 = blockIdx.x * NU;
  const int grp = blockIdx.x >> 4;   // 16 WGs per barrier group

  // Stage weight slices fp32 -> bf16 into LDS, swizzled: idx ^= (row&7)<<3
  for (int idx = tid; idx < NR * NH; idx += 512) {
    int r = idx >> 10;
    int k = idx & (NH - 1);
    int g = r >> 2, uu = r & 3;
    Wh_l[(r << 10) | (k ^ ((r & 7) << 3))] = f2bf(Whh[(g * NH + u0 + uu) * NH + k]);
  }
  for (int idx = tid; idx < NR * NI; idx += 512) {
    int r = idx >> 8;
    int k = idx & (NI - 1);
    int g = r >> 2, uu = r & 3;
    Wi_l[(r << 8) | (k ^ ((r & 7) << 3))] = f2bf(Wih[(g * NH + u0 + uu) * NI + k]);
  }
  if (tid < NR) {
    int g = tid >> 2, uu = tid & 3;
    bias_l[tid] = bih[g * NH + u0 + uu] + bhh[g * NH + u0 + uu];
  }
  __syncthreads();

  const int wave = tid >> 6;
  const int lane = tid & 63;
  const int lr = lane & 15;   // A row within M-tile / B gate-row / D col
  const int lq = lane >> 4;   // k-subgroup / D row-group
  const int m = wave & 3;     // M tile (16 batches)
  const int kh = wave >> 2;   // K half

  const int eb = tid >> 2;    // elementwise batch (threads 0..255)
  const int eu = tid & 3;     // elementwise unit
  float c_state = 0.f;

  const int arow = m * 16 + lr;
  const unsigned short* wi_row = Wi_l + lr * NI;
  const unsigned short* wh_row = Wh_l + lr * NH;
  const int swz = (lr & 7) << 3;

#define COMPUTE_AX(T_, AX0, AX1)                                                \
  do {                                                                          \
    AX0 = (f32x4){0.f, 0.f, 0.f, 0.f};                                          \
    AX1 = (f32x4){0.f, 0.f, 0.f, 0.f};                                          \
    const unsigned short* xrow = xbf + ((T_) * NB + arow) * NI + lq * 8;        \
    _Pragma("unroll")                                                           \
    for (int kk2 = 0; kk2 < 2; ++kk2) {                                         \
      int kk = kh * 4 + kk2 * 2;                                                \
      bf16x8 a0 = *(const bf16x8*)(xrow + kk * 32);                             \
      bf16x8 b0 = *(const bf16x8*)(wi_row + ((kk * 32 + lq * 8) ^ swz));        \
      AX0 = __builtin_amdgcn_mfma_f32_16x16x32_bf16(a0, b0, AX0, 0, 0, 0);      \
      bf16x8 a1 = *(const bf16x8*)(xrow + (kk + 1) * 32);                       \
      bf16x8 b1 = *(const bf16x8*)(wi_row + (((kk + 1) * 32 + lq * 8) ^ swz));  \
      AX1 = __builtin_amdgcn_mfma_f32_16x16x32_bf16(a1, b1, AX1, 0, 0, 0);      \
    }                                                                           \
  } while (0)

  f32x4 ax0, ax1;
  COMPUTE_AX(0, ax0, ax1);

  for (int t = 0; t < NT; ++t) {
    f32x4 ah0 = {0.f, 0.f, 0.f, 0.f};
    f32x4 ah1 = {0.f, 0.f, 0.f, 0.f};
    // h contribution: K = 1024, this K-half covers kk = kh*16 .. kh*16+15.
    // PLAIN cached loads (the one change vs R6): per-XCD L2 fetches each
    // h(t-1) line once from LLC and serves all 32 co-located WGs.
    if (t > 0) {
      const unsigned long long* hrow =
          (const unsigned long long*)(hall + ((t - 1) * NB + arow) * NH) + lq * 2;
#pragma unroll
      for (int kk2 = 0; kk2 < 8; ++kk2) {
        int kk = kh * 16 + kk2 * 2;
        FragQ a0, a1;
        a0.q[0] = hrow[kk * 8 + 0];
        a0.q[1] = hrow[kk * 8 + 1];
        a1.q[0] = hrow[kk * 8 + 8];
        a1.q[1] = hrow[kk * 8 + 9];
        bf16x8 b0 = *(const bf16x8*)(wh_row + ((kk * 32 + lq * 8) ^ swz));
        bf16x8 b1 = *(const bf16x8*)(wh_row + (((kk + 1) * 32 + lq * 8) ^ swz));
        ah0 = __builtin_amdgcn_mfma_f32_16x16x32_bf16(a0.v, b0, ah0, 0, 0, 0);
        ah1 = __builtin_amdgcn_mfma_f32_16x16x32_bf16(a1.v, b1, ah1, 0, 0, 0);
      }
    }
    f32x4 z4 = (ah0 + ah1) + (ax0 + ax1);
    // D layout: col = lane&15 (gate row), row = (lane>>4)*4 + j (batch)
#pragma unroll
    for (int j = 0; j < 4; ++j)
      zbuf[kh][m * 16 + lq * 4 + j][lr] = z4[j];
    __syncthreads();

    if (tid < 256) {
      float zi = zbuf[0][eb][0 * NU + eu] + zbuf[1][eb][0 * NU + eu] + bias_l[0 * NU + eu];
      float zf = zbuf[0][eb][1 * NU + eu] + zbuf[1][eb][1 * NU + eu] + bias_l[1 * NU + eu];
      float zg = zbuf[0][eb][2 * NU + eu] + zbuf[1][eb][2 * NU + eu] + bias_l[2 * NU + eu];
      float zo = zbuf[0][eb][3 * NU + eu] + zbuf[1][eb][3 * NU + eu] + bias_l[3 * NU + eu];
      float ig = 1.f / (1.f + __expf(-zi));
      float fg = 1.f / (1.f + __expf(-zf));
      float gg = tanhf(zg);
      float og = 1.f / (1.f + __expf(-zo));
      c_state = fg * c_state + ig * gg;
      float hv = og * tanhf(c_state);
      hstage[eb * NU + eu] = f2bf(hv);
    }
    __syncthreads();

    // Wave 0 publishes the WG's h-slice: 64 lanes x 8B, agent-scope (sc1,
    // write to LLC, never dirty in any L2).
    if (wave == 0) {
      unsigned long long hq = *(const unsigned long long*)(hstage + lane * NU);
      __hip_atomic_store((unsigned long long*)(hall + (t * NB + lane) * NH + u0), hq,
                         __ATOMIC_RELAXED, __HIP_MEMORY_SCOPE_AGENT);
    }
    // Tree-barrier arrival: drain wave 0's h-stores (sc1 -> LLC) with an
    // explicit vmcnt(0) -- NO implicit release fence / L2 writeback -- then
    // relaxed add to this WG's group counter; the group's last arriver
    // (data-dependent on the returned count) bumps the root.
    if (tid == 0) {
      asm volatile("s_waitcnt vmcnt(0)" ::: "memory");
      unsigned int old = __hip_atomic_fetch_add(bar + (grp + 1) * 32, 1u,
                                                __ATOMIC_RELAXED, __HIP_MEMORY_SCOPE_AGENT);
      if (old == (unsigned int)(t * GSZ + (GSZ - 1)))
        __hip_atomic_fetch_add(bar, 1u, __ATOMIC_RELAXED, __HIP_MEMORY_SCOPE_AGENT);
    }
    // Overlap the barrier round-trip with next step's x-MFMAs (h-independent).
    if (t + 1 < NT) COMPUTE_AX(t + 1, ax0, ax1);
    // Spin on the root (relaxed; h-loads are fenced behind __syncthreads()).
    if (tid == 0) {
      const unsigned int target = (unsigned int)(t + 1) * NGRP;
      while (__hip_atomic_load(bar, __ATOMIC_RELAXED, __HIP_MEMORY_SCOPE_AGENT) < target)
        __builtin_amdgcn_s_sleep(1);
    }
    __syncthreads();
  }
#undef COMPUTE_AX
}

// ---------------------------------------------------------------- y = h @ Wout^T + b
__global__ void __launch_bounds__(256) outproj_kernel(
    const unsigned short* __restrict__ hall,  // [T*B][H] bf16
    const float* __restrict__ Wout,           // [O][H]
    const float* __restrict__ bout,           // [O]
    float* __restrict__ y) {                  // [B][T][O] fp32
  __shared__ __align__(16) unsigned short At[64 * 64];
  __shared__ __align__(16) unsigned short Bt[64 * 64];
  const int tid = threadIdx.x;
  const int row0 = blockIdx.x * 64;
  const int col0 = blockIdx.y * 64;
  const int wave = tid >> 6, lane = tid & 63, lr = lane & 15, lq = lane >> 4;
  f32x4 acc[4];
#pragma unroll
  for (int n = 0; n < 4; ++n) acc[n] = (f32x4){0.f, 0.f, 0.f, 0.f};
  const int rr = tid >> 4;
  const int kk4 = (tid & 15) * 4;

  for (int kc = 0; kc < NH / 64; ++kc) {
#pragma unroll
    for (int p = 0; p < 4; ++p) {
      int r = rr + p * 16;
      ushort4 va = *(const ushort4*)(hall + (size_t)(row0 + r) * NH + kc * 64 + kk4);
      *(ushort4*)(At + r * 64 + (kk4 ^ ((r & 7) << 3))) = va;
      float4 vb = *(const float4*)(Wout + (size_t)(col0 + r) * NH + kc * 64 + kk4);
      ushort4 wb;
      wb.x = f2bf(vb.x); wb.y = f2bf(vb.y); wb.z = f2bf(vb.z); wb.w = f2bf(vb.w);
      *(ushort4*)(Bt + r * 64 + (kk4 ^ ((r & 7) << 3))) = wb;
    }
    __syncthreads();
#pragma unroll
    for (int kk = 0; kk < 2; ++kk) {
      int kb = kk * 32 + lq * 8;
      bf16x8 af = *(const bf16x8*)(At + (wave * 16 + lr) * 64 + (kb ^ ((lr & 7) << 3)));
#pragma unroll
      for (int n = 0; n < 4; ++n) {
        bf16x8 bf = *(const bf16x8*)(Bt + (n * 16 + lr) * 64 + (kb ^ ((lr & 7) << 3)));
        acc[n] = __builtin_amdgcn_mfma_f32_16x16x32_bf16(af, bf, acc[n], 0, 0, 0);
      }
    }
    __syncthreads();
  }
#pragma unroll
  for (int n = 0; n < 4; ++n) {
    int o = col0 + n * 16 + lr;
    float bo = bout[o];
#pragma unroll
    for (int j = 0; j < 4; ++j) {
      int r = row0 + wave * 16 + lq * 4 + j;  // r = t*NB + b
      int b = r & (NB - 1);
      int t = r >> 6;
      y[(size_t)((b << 9) | t) * NO + o] = acc[n][j] + bo;
    }
  }
}

// ---------------------------------------------------------------- launch
extern "C" void kernel_launch(void* const* d_in, const int* in_sizes, int n_in,
                              void* d_out, int out_size, void* d_ws, size_t ws_size,
                              hipStream_t stream) {
  const float* x    = (const float*)d_in[0];
  const float* Wih  = (const float*)d_in[1];
  const float* Whh  = (const float*)d_in[2];
  const float* bih  = (const float*)d_in[3];
  const float* bhh  = (const float*)d_in[4];
  const float* Wout = (const float*)d_in[5];
  const float* bout = (const float*)d_in[6];
  float* y = (float*)d_out;

  // ws layout: xbf (16 MB) | hall (64 MB)  => 80 MB needed
  unsigned short* xbf  = (unsigned short*)d_ws;
  unsigned short* hall = xbf + (size_t)NT * NB * NI;
  // Barrier counters live in d_out[0..543]: zeroed by xpose_kernel before the
  // coop kernel, fully overwritten by outproj_kernel afterwards.
  unsigned int* bar = (unsigned int*)d_out;

  hipLaunchKernelGGL(xpose_kernel, dim3(1024), dim3(256), 0, stream, x, xbf, bar);

  void* args[7];
  args[0] = (void*)&xbf;
  args[1] = (void*)&Wih;
  args[2] = (void*)&Whh;
  args[3] = (void*)&bih;
  args[4] = (void*)&bhh;
  args[5] = (void*)&hall;
  args[6] = (void*)&bar;
  hipLaunchCooperativeKernel(lstm_kernel, dim3(NWG), dim3(512), args, 0u, stream);

  hipLaunchKernelGGL(outproj_kernel, dim3(512, 4), dim3(256), 0, stream,
                     hall, Wout, bout, y);
}